// Round 5
// baseline (279.511 us; speedup 1.0000x reference)
//
#include <hip/hip_runtime.h>
#include <hip/hip_bf16.h>

#define B_   8
#define LS_  1024
#define LT_  1024
#define D_   768
#define INV_REG 10.0f
#define EPS_ 1e-8f
#define AVAL (1.0f/1024.0f)
#define BVAL (1.0f/1024.0f)
#define NITER 10

typedef __attribute__((ext_vector_type(8))) short bf16x8;
typedef __attribute__((ext_vector_type(4))) float f32x4;

__device__ inline unsigned short f2bf(float f) {
    __hip_bfloat16 h = __float2bfloat16(f);
    return __builtin_bit_cast(unsigned short, h);
}

// ---------------- init: zero denT[NITER], partialB, out; denS = AVAL-EPS (=> u0 = 1)
__global__ __launch_bounds__(256) void init_bufs(float* denS, float* denT, float* partialB, float* out) {
    int i = blockIdx.x * 256 + threadIdx.x;
    if (i < B_*LS_) denS[i] = AVAL - EPS_;
    if (i < NITER*B_*LT_) denT[i] = 0.0f;
    if (i < B_) partialB[i] = 0.0f;
    if (i == 0) out[0] = 0.0f;
}

// ---------------- prep: row sumsq + bf16 cast. 192 threads = 768/4; blocks 0..8191 student, 8192.. teacher
__global__ __launch_bounds__(192) void prep_rows(const float* __restrict__ S, const float* __restrict__ T,
                                                 __hip_bfloat16* __restrict__ sbf, __hip_bfloat16* __restrict__ tbf,
                                                 float* __restrict__ sqS, float* __restrict__ sqT) {
    int bid = blockIdx.x;
    bool teach = bid >= B_*LS_;
    int row = teach ? bid - B_*LS_ : bid;
    const float* src = (teach ? T : S) + (size_t)row * D_;
    __hip_bfloat16* dst = (teach ? tbf : sbf) + (size_t)row * D_;
    int t = threadIdx.x;
    float4 v = *(const float4*)(src + t * 4);
    float ss = v.x*v.x + v.y*v.y + v.z*v.z + v.w*v.w;
    ushort4 o;
    o.x = f2bf(v.x);
    o.y = f2bf(v.y);
    o.z = f2bf(v.z);
    o.w = f2bf(v.w);
    *(ushort4*)(dst + t * 4) = o;
    for (int off = 32; off; off >>= 1) ss += __shfl_down(ss, off);
    __shared__ float red[3];
    int wid = t >> 6, lane = t & 63;
    if (lane == 0) red[wid] = ss;
    __syncthreads();
    if (t == 0) (teach ? sqT : sqS)[row] = red[0] + red[1] + red[2];
}

// ---------------- GEMM + cdist epilogue: C[b][s][t] = sqrt(max(sqS+sqT-2*S.T, 0))
__device__ inline void gload_lds16(const void* g, void* l) {
    __builtin_amdgcn_global_load_lds((const __attribute__((address_space(1))) void*)g,
                                     (__attribute__((address_space(3))) void*)l, 16, 0, 0);
}

// 1D grid, 512 blocks: b = bid&7 (XCD pinning), tile = bid>>3 -> 8x8 tiles of 128x128
__global__ __launch_bounds__(256) void gemm_cdist(const __hip_bfloat16* __restrict__ S,
                                                  const __hip_bfloat16* __restrict__ T,
                                                  const float* __restrict__ sqS, const float* __restrict__ sqT,
                                                  float* __restrict__ C) {
    __shared__ __hip_bfloat16 As[128 * 32];
    __shared__ __hip_bfloat16 Bs[128 * 32];
    const int bid  = blockIdx.x;
    const int b    = bid & 7;
    const int tile = bid >> 3;
    const int brow = (tile >> 3) * 128;
    const int bcol = (tile & 7) * 128;
    const int tid  = threadIdx.x;
    const int wid  = tid >> 6, lane = tid & 63;
    const int wr = wid >> 1, wc = wid & 1;            // 2x2 waves, each 64x64
    const __hip_bfloat16* Sg = S + ((size_t)b * LS_ + brow) * D_;
    const __hip_bfloat16* Tg = T + ((size_t)b * LT_ + bcol) * D_;

    f32x4 acc[4][4] = {};
    const int r16 = lane & 15, kg = lane >> 4;        // frag row / k-group

    for (int k0 = 0; k0 < D_; k0 += 32) {
        // stage 128x32 bf16 tiles (8 KB each) via global_load_lds width=16
        #pragma unroll
        for (int j = 0; j < 2; ++j) {
            int lin = j * 256 + tid;                  // 16B chunk id (512 per tile)
            int row = lin >> 2, c8 = (lin & 3) * 8;
            __hip_bfloat16* la = As + (size_t)(j * 256 + wid * 64) * 8;  // wave-uniform base
            __hip_bfloat16* lb = Bs + (size_t)(j * 256 + wid * 64) * 8;
            gload_lds16(Sg + (size_t)row * D_ + k0 + c8, la);
            gload_lds16(Tg + (size_t)row * D_ + k0 + c8, lb);
        }
        __syncthreads();
        bf16x8 af[4], bfr[4];
        #pragma unroll
        for (int f = 0; f < 4; ++f) {
            af[f]  = *(const bf16x8*)(As + (wr * 64 + f * 16 + r16) * 32 + kg * 8);
            bfr[f] = *(const bf16x8*)(Bs + (wc * 64 + f * 16 + r16) * 32 + kg * 8);
        }
        #pragma unroll
        for (int i = 0; i < 4; ++i)
            #pragma unroll
            for (int j = 0; j < 4; ++j)
                acc[i][j] = __builtin_amdgcn_mfma_f32_16x16x32_bf16(af[i], bfr[j], acc[i][j], 0, 0, 0);
        __syncthreads();
    }

    // epilogue: C/D map col=lane&15, row=(lane>>4)*4+reg
    #pragma unroll
    for (int i = 0; i < 4; ++i) {
        int gr0 = brow + wr * 64 + i * 16 + (lane >> 4) * 4;
        #pragma unroll
        for (int j = 0; j < 4; ++j) {
            int gc = bcol + wc * 64 + j * 16 + (lane & 15);
            float st = sqT[b * LT_ + gc];
            #pragma unroll
            for (int r = 0; r < 4; ++r) {
                float ss = sqS[b * LS_ + gr0 + r];
                float d2 = ss + st - 2.0f * acc[i][j][r];
                C[((size_t)b * LS_ + (gr0 + r)) * LT_ + gc] = sqrtf(fmaxf(d2, 0.0f));
            }
        }
    }
}

// ---------------- pass V: denT[b][t] += sum_s exp(-C*10) * u_s,  u_s = AVAL/(denS+eps)
// 256 blocks: b = bid&7 (XCD-pinned), 32 s-rows per block, thread covers 4 t-cols (float4)
__global__ __launch_bounds__(256) void pass_v(const float* __restrict__ C, const float* __restrict__ denS,
                                              float* __restrict__ denT) {
    int bid = blockIdx.x;
    int b = bid & 7;
    int s0 = (bid >> 3) * 32;
    __shared__ float ush[32];
    if (threadIdx.x < 32) ush[threadIdx.x] = AVAL / (denS[b * LS_ + s0 + threadIdx.x] + EPS_);
    __syncthreads();
    const float* Cb = C + ((size_t)b << 20) + ((size_t)s0 << 10);
    int t4 = threadIdx.x * 4;
    float ax = 0.f, ay = 0.f, az = 0.f, aw = 0.f;
    #pragma unroll 4
    for (int i = 0; i < 32; ++i) {
        const float4 c = *(const float4*)(Cb + ((size_t)i << 10) + t4);
        float u = ush[i];
        ax += __expf(-c.x * INV_REG) * u;
        ay += __expf(-c.y * INV_REG) * u;
        az += __expf(-c.z * INV_REG) * u;
        aw += __expf(-c.w * INV_REG) * u;
    }
    float* dT = denT + b * LT_ + t4;
    atomicAdd(dT + 0, ax);
    atomicAdd(dT + 1, ay);
    atomicAdd(dT + 2, az);
    atomicAdd(dT + 3, aw);
}

// ---------------- pass U: denS[b][s] = sum_t exp(-C*10) * v_t,  v_t = BVAL/(denT+eps)
// 2048 blocks: b = bid&7, 4 rows per block (one per wave), wave-reduce, no LDS
__global__ __launch_bounds__(256) void pass_u(const float* __restrict__ C, const float* __restrict__ denT,
                                              float* __restrict__ denS) {
    int bid = blockIdx.x;
    int b = bid & 7;
    int w = threadIdx.x >> 6, lane = threadIdx.x & 63;
    int s = (bid >> 3) * 4 + w;
    const float* Crow = C + ((size_t)b << 20) + ((size_t)s << 10);
    const float* dT = denT + (b << 10);
    float acc = 0.0f;
    #pragma unroll
    for (int k = 0; k < 4; ++k) {
        int t = k * 256 + lane * 4;
        float4 c = *(const float4*)(Crow + t);
        float4 dv = *(const float4*)(dT + t);
        acc += __expf(-c.x * INV_REG) * (BVAL / (dv.x + EPS_));
        acc += __expf(-c.y * INV_REG) * (BVAL / (dv.y + EPS_));
        acc += __expf(-c.z * INV_REG) * (BVAL / (dv.z + EPS_));
        acc += __expf(-c.w * INV_REG) * (BVAL / (dv.w + EPS_));
    }
    for (int off = 32; off; off >>= 1) acc += __shfl_down(acc, off);
    if (lane == 0) denS[b * LS_ + s] = acc;
}

// ---------------- final: partialB[b] += u_s * sum_t K*C*v_t  (uses final denS, iter-9 denT)
__global__ __launch_bounds__(256) void final_pass(const float* __restrict__ C, const float* __restrict__ denT9,
                                                  const float* __restrict__ denS, float* __restrict__ partialB) {
    int bid = blockIdx.x;
    int b = bid & 7;
    int w = threadIdx.x >> 6, lane = threadIdx.x & 63;
    int s = (bid >> 3) * 4 + w;
    const float* Crow = C + ((size_t)b << 20) + ((size_t)s << 10);
    const float* dT = denT9 + (b << 10);
    float acc = 0.0f;
    #pragma unroll
    for (int k = 0; k < 4; ++k) {
        int t = k * 256 + lane * 4;
        float4 c = *(const float4*)(Crow + t);
        float4 dv = *(const float4*)(dT + t);
        acc += __expf(-c.x * INV_REG) * c.x * (BVAL / (dv.x + EPS_));
        acc += __expf(-c.y * INV_REG) * c.y * (BVAL / (dv.y + EPS_));
        acc += __expf(-c.z * INV_REG) * c.z * (BVAL / (dv.z + EPS_));
        acc += __expf(-c.w * INV_REG) * c.w * (BVAL / (dv.w + EPS_));
    }
    for (int off = 32; off; off >>= 1) acc += __shfl_down(acc, off);
    __shared__ float red[4];
    if (lane == 0) red[w] = acc * (AVAL / (denS[b * LS_ + s] + EPS_));
    __syncthreads();
    if (threadIdx.x == 0) atomicAdd(&partialB[b], red[0] + red[1] + red[2] + red[3]);
}

__global__ void finalize(const float* __restrict__ partialB, float* __restrict__ out) {
    if (threadIdx.x == 0) {
        float s = 0.0f;
        for (int i = 0; i < B_; ++i) s += partialB[i];
        out[0] = s / (float)B_;
    }
}

extern "C" void kernel_launch(void* const* d_in, const int* in_sizes, int n_in,
                              void* d_out, int out_size, void* d_ws, size_t ws_size,
                              hipStream_t stream) {
    const float* S = (const float*)d_in[0];
    const float* T = (const float*)d_in[1];
    float* out = (float*)d_out;
    char* ws = (char*)d_ws;

    // workspace layout (bytes); total ~59.3 MB
    const size_t offC    = 0;                                  // 8*1024*1024 f32 = 33554432
    const size_t offSbf  = offC   + (size_t)B_*LS_*LT_*4;      // 8*1024*768 bf16 = 12582912
    const size_t offTbf  = offSbf + (size_t)B_*LS_*D_*2;
    const size_t offSqS  = offTbf + (size_t)B_*LT_*D_*2;       // 8192 f32
    const size_t offSqT  = offSqS + (size_t)B_*LS_*4;
    const size_t offDenS = offSqT + (size_t)B_*LT_*4;
    const size_t offDenT = offDenS + (size_t)B_*LS_*4;         // NITER * 8192 f32
    const size_t offPart = offDenT + (size_t)NITER*B_*LT_*4;
    const size_t need    = offPart + 256;
    if (ws_size < need) return;  // fail loudly (validation mismatch) rather than corrupt

    float* C    = (float*)(ws + offC);
    __hip_bfloat16* sbf = (__hip_bfloat16*)(ws + offSbf);
    __hip_bfloat16* tbf = (__hip_bfloat16*)(ws + offTbf);
    float* sqS  = (float*)(ws + offSqS);
    float* sqT  = (float*)(ws + offSqT);
    float* denS = (float*)(ws + offDenS);
    float* denT = (float*)(ws + offDenT);
    float* part = (float*)(ws + offPart);

    int initN = NITER * B_ * LT_;
    init_bufs<<<(initN + 255) / 256, 256, 0, stream>>>(denS, denT, part, out);
    prep_rows<<<2 * B_ * LS_, 192, 0, stream>>>(S, T, sbf, tbf, sqS, sqT);
    gemm_cdist<<<512, 256, 0, stream>>>(sbf, tbf, sqS, sqT, C);

    for (int i = 0; i < NITER; ++i) {
        pass_v<<<256, 256, 0, stream>>>(C, denS, denT + (size_t)i * B_ * LT_);
        pass_u<<<2048, 256, 0, stream>>>(C, denT + (size_t)i * B_ * LT_, denS);
    }
    final_pass<<<2048, 256, 0, stream>>>(C, denT + (size_t)(NITER - 1) * B_ * LT_, denS, part);
    finalize<<<1, 64, 0, stream>>>(part, out);
}